// Round 2
// baseline (18.249 us; speedup 1.0000x reference)
//
#include <hip/hip_runtime.h>

#define S_LEN 2048
#define H_NUM 8
#define D_DIM 64
#define W_WIN 32
#define TS 32
#define ROWS (TS + W_WIN - 1)   // 63
#define PADK 68                 // floats per LDS row: 16B-aligned stride, breaks stride-64 bank pathology

__global__ __launch_bounds__(256, 4) void swa_gated_kernel(
    const float* __restrict__ q, const float* __restrict__ k,
    const float* __restrict__ v, const float* __restrict__ a,
    const float* __restrict__ bgate, float* __restrict__ out)
{
    __shared__ __align__(16) float k_lds[ROWS][PADK];
    __shared__ __align__(16) float v_lds[ROWS][PADK];
    __shared__ float w_lds[TS][W_WIN + 1];
    __shared__ float a_lds[ROWS + 1];
    __shared__ float b_lds[TS];

    const int tid  = threadIdx.x;
    const int bid  = blockIdx.x;
    const int tile = bid & 63;          // S/TS = 64 tiles
    const int h    = (bid >> 6) & 7;    // 8 heads
    const int bb   = bid >> 9;          // batch
    const int s0   = tile * TS;
    const size_t HD = (size_t)H_NUM * D_DIM;   // 512

    // ---- stage k/v rows [s0-31, s0+TS) into LDS (float4, coalesced) ----
    for (int idx = tid; idx < ROWS * 16; idx += 256) {
        int r  = idx >> 4;
        int c4 = idx & 15;
        int seq = s0 - (W_WIN - 1) + r;
        int seqc = seq < 0 ? 0 : seq;   // clamped; invalid masked later
        size_t base = ((size_t)(bb * S_LEN + seqc)) * HD + (size_t)h * D_DIM + c4 * 4;
        float4 kv = *(const float4*)(k + base);
        float4 vv = *(const float4*)(v + base);
        *(float4*)&k_lds[r][c4 * 4] = kv;
        *(float4*)&v_lds[r][c4 * 4] = vv;
    }
    for (int r = tid; r < ROWS; r += 256) {
        int seq = s0 - (W_WIN - 1) + r;
        int seqc = seq < 0 ? 0 : seq;
        a_lds[r] = a[((size_t)(bb * S_LEN + seqc)) * H_NUM + h];
    }
    if (tid < TS) {
        b_lds[tid] = bgate[((size_t)(bb * S_LEN + s0 + tid)) * H_NUM + h];
    }
    __syncthreads();

    // ---- score phase: thread -> (query qi, window positions wb+8j) ----
    {
        const int qi = tid >> 3;        // 0..31
        const int wb = tid & 7;         // 0..7
        const float* qrow = q + ((size_t)(bb * S_LEN + s0 + qi)) * HD + (size_t)h * D_DIM;
        float acc[4] = {0.f, 0.f, 0.f, 0.f};
        #pragma unroll
        for (int d4 = 0; d4 < 16; ++d4) {
            float4 qv = *(const float4*)(qrow + d4 * 4);
            #pragma unroll
            for (int j = 0; j < 4; ++j) {
                int row = qi + wb + 8 * j;   // seq = s0-31+(qi+w)
                float4 kv = *(const float4*)&k_lds[row][d4 * 4];
                acc[j] += qv.x * kv.x + qv.y * kv.y + qv.z * kv.z + qv.w * kv.w;
            }
        }
        const float scale = 0.125f;   // 1/sqrt(64)
        const float bg = b_lds[qi];
        #pragma unroll
        for (int j = 0; j < 4; ++j) {
            int w   = wb + 8 * j;
            int row = qi + w;
            int seq = s0 + qi - (W_WIN - 1) + w;
            float gate = 1.0f / (1.0f + __expf(-(a_lds[row] * bg)));
            float wt = acc[j] * scale * gate;
            w_lds[qi][w] = (seq >= 0) ? wt : 0.0f;
        }
    }
    __syncthreads();

    // ---- PV phase: thread -> (query qi, 8-dim chunk db) ----
    {
        const int qi = tid >> 3;        // 0..31
        const int db = tid & 7;         // 0..7 -> dims [db*8, db*8+8)
        float o[8];
        #pragma unroll
        for (int i = 0; i < 8; ++i) o[i] = 0.f;
        #pragma unroll
        for (int w = 0; w < W_WIN; ++w) {
            float wt = w_lds[qi][w];
            int row = qi + w;
            #pragma unroll
            for (int i4 = 0; i4 < 2; ++i4) {
                float4 vv = *(const float4*)&v_lds[row][db * 8 + i4 * 4];
                o[i4*4+0] += wt * vv.x;
                o[i4*4+1] += wt * vv.y;
                o[i4*4+2] += wt * vv.z;
                o[i4*4+3] += wt * vv.w;
            }
        }
        float* orow = out + ((size_t)(bb * S_LEN + s0 + qi)) * HD + (size_t)h * D_DIM + db * 8;
        #pragma unroll
        for (int i4 = 0; i4 < 2; ++i4) {
            *(float4*)(orow + i4 * 4) =
                make_float4(o[i4*4+0], o[i4*4+1], o[i4*4+2], o[i4*4+3]);
        }
    }
}

extern "C" void kernel_launch(void* const* d_in, const int* in_sizes, int n_in,
                              void* d_out, int out_size, void* d_ws, size_t ws_size,
                              hipStream_t stream) {
    const float* q  = (const float*)d_in[0];
    const float* k  = (const float*)d_in[1];
    const float* v  = (const float*)d_in[2];
    const float* a  = (const float*)d_in[3];
    const float* bg = (const float*)d_in[4];
    float* out = (float*)d_out;

    dim3 grid(2 /*B*/ * H_NUM * (S_LEN / TS));   // 1024 blocks
    swa_gated_kernel<<<grid, 256, 0, stream>>>(q, k, v, a, bg, out);
}

// Round 3
// 11.723 us; speedup vs baseline: 1.5568x; 1.5568x over previous
//
#include <hip/hip_runtime.h>
#include <hip/hip_bf16.h>

#define S_LEN 2048
#define H_NUM 8
#define D_DIM 64
#define W_WIN 32
#define TS 32
#define NROWS 63            // staged k/v rows: [s0-31, s0+32)

typedef short bf16x8 __attribute__((ext_vector_type(8)));
typedef float f32x4  __attribute__((ext_vector_type(4)));

// XOR-swizzle within a 128-byte LDS row: spreads 16B chunks of different
// rows across banks (bits 4-6 of byte offset XOR row&7). Bijective per row.
__device__ __forceinline__ int swz(int row, int byte_in_row) {
    return (row << 7) + (byte_in_row ^ ((row & 7) << 4));
}

__device__ __forceinline__ unsigned short f2bf(float x) {
    __hip_bfloat16 h = __float2bfloat16(x);
    return *reinterpret_cast<unsigned short*>(&h);
}

__global__ __launch_bounds__(256) void swa_gated_mfma(
    const float* __restrict__ q, const float* __restrict__ k,
    const float* __restrict__ v, const float* __restrict__ a,
    const float* __restrict__ bgate, float* __restrict__ out)
{
    // all tiles row-major [R][64] bf16, 128 B rows, XOR-swizzled
    __shared__ __align__(16) unsigned short q_s[32 * 64];   // 4 KB
    __shared__ __align__(16) unsigned short k_s[64 * 64];   // 8 KB (row 63 garbage, always masked)
    __shared__ __align__(16) unsigned short vT_s[64 * 64];  // 8 KB [d][row]
    __shared__ __align__(16) unsigned short w_s[32 * 64];   // 4 KB
    __shared__ float a_lds[64];
    __shared__ float b_lds[32];

    char* qb  = (char*)q_s;
    char* kb  = (char*)k_s;
    char* vtb = (char*)vT_s;
    char* wb  = (char*)w_s;

    const int tid = threadIdx.x;
    // bijective XCD swizzle: 1024 blocks, 8 XCDs -> each XCD gets a
    // contiguous orig-range (all 64 tiles of 2 heads) for halo L2 reuse
    const int bid  = blockIdx.x;
    const int orig = ((bid & 7) << 7) | (bid >> 3);
    const int tile = orig & 63;          // 64 tiles of TS=32
    const int h    = (orig >> 6) & 7;
    const int bb   = orig >> 9;
    const int s0   = tile * TS;
    const size_t HD = (size_t)H_NUM * D_DIM;   // 512

    // ---- stage k (bf16, row-major) and v (bf16, transposed) ----
    for (int idx = tid; idx < NROWS * 16; idx += 256) {
        int r  = idx >> 4;
        int c4 = idx & 15;
        int seq  = s0 - (W_WIN - 1) + r;
        int seqc = seq < 0 ? 0 : seq;       // invalid rows masked later
        size_t base = ((size_t)(bb * S_LEN + seqc)) * HD + (size_t)h * D_DIM + c4 * 4;
        float4 kv = *(const float4*)(k + base);
        float4 vv = *(const float4*)(v + base);
        union { unsigned short u[4]; uint2 p; } pk;
        pk.u[0] = f2bf(kv.x); pk.u[1] = f2bf(kv.y);
        pk.u[2] = f2bf(kv.z); pk.u[3] = f2bf(kv.w);
        *(uint2*)(kb + swz(r, c4 * 8)) = pk.p;
        int d0 = c4 * 4;
        *(unsigned short*)(vtb + swz(d0 + 0, r * 2)) = f2bf(vv.x);
        *(unsigned short*)(vtb + swz(d0 + 1, r * 2)) = f2bf(vv.y);
        *(unsigned short*)(vtb + swz(d0 + 2, r * 2)) = f2bf(vv.z);
        *(unsigned short*)(vtb + swz(d0 + 3, r * 2)) = f2bf(vv.w);
    }
    // stage q (bf16, row-major)
    for (int idx = tid; idx < 32 * 16; idx += 256) {
        int r  = idx >> 4;
        int c4 = idx & 15;
        size_t base = ((size_t)(bb * S_LEN + s0 + r)) * HD + (size_t)h * D_DIM + c4 * 4;
        float4 qv = *(const float4*)(q + base);
        union { unsigned short u[4]; uint2 p; } pq;
        pq.u[0] = f2bf(qv.x); pq.u[1] = f2bf(qv.y);
        pq.u[2] = f2bf(qv.z); pq.u[3] = f2bf(qv.w);
        *(uint2*)(qb + swz(r, c4 * 8)) = pq.p;
    }
    if (tid < 64) {
        int seq = s0 - (W_WIN - 1) + tid;
        int sc  = seq < 0 ? 0 : (seq > S_LEN - 1 ? S_LEN - 1 : seq);
        a_lds[tid] = a[((size_t)(bb * S_LEN + sc)) * H_NUM + h];
        // zero vT[:, 63]: PV reads k=63; W[:,63]==0 but 0*NaN would poison MFMA
        *(unsigned short*)(vtb + swz(tid, 63 * 2)) = 0;
    }
    if (tid < 32) {
        b_lds[tid] = bgate[((size_t)(bb * S_LEN + s0 + tid)) * H_NUM + h];
    }
    __syncthreads();

    const int wid = tid >> 6;
    const int l   = tid & 63;
    const int mi  = wid & 1;             // M-tile (query block of 16)
    const int nj0 = (wid >> 1) << 1;     // this wave's N-tile pair: {nj0, nj0+1}
    const int lr  = l & 15;              // row/col within 16-tile
    const int lk  = l >> 4;              // k-chunk 0..3

    // ---- scores: S[32 x 64] = Q * K^T (dense, band-masked after) ----
    {
        bf16x8 aq0 = *(const bf16x8*)(qb + swz(mi * 16 + lr, lk * 16));
        bf16x8 aq1 = *(const bf16x8*)(qb + swz(mi * 16 + lr, lk * 16 + 64));
        f32x4 c0 = {0.f, 0.f, 0.f, 0.f};
        f32x4 c1 = {0.f, 0.f, 0.f, 0.f};
        bf16x8 b00 = *(const bf16x8*)(kb + swz(nj0 * 16 + lr,      lk * 16));
        bf16x8 b01 = *(const bf16x8*)(kb + swz(nj0 * 16 + lr,      lk * 16 + 64));
        bf16x8 b10 = *(const bf16x8*)(kb + swz(nj0 * 16 + 16 + lr, lk * 16));
        bf16x8 b11 = *(const bf16x8*)(kb + swz(nj0 * 16 + 16 + lr, lk * 16 + 64));
        c0 = __builtin_amdgcn_mfma_f32_16x16x32_bf16(aq0, b00, c0, 0, 0, 0);
        c0 = __builtin_amdgcn_mfma_f32_16x16x32_bf16(aq1, b01, c0, 0, 0, 0);
        c1 = __builtin_amdgcn_mfma_f32_16x16x32_bf16(aq0, b10, c1, 0, 0, 0);
        c1 = __builtin_amdgcn_mfma_f32_16x16x32_bf16(aq1, b11, c1, 0, 0, 0);

        // gate + mask + store W (bf16) -- select, not multiply (NaN-safe)
        const float scale = 0.125f;
        const int r0 = nj0 * 16 + lr;
        const int r1 = r0 + 16;
        const float av0 = a_lds[r0];
        const float av1 = a_lds[r1];
        #pragma unroll
        for (int i = 0; i < 4; ++i) {
            int qi = mi * 16 + lk * 4 + i;   // query within tile
            float bgv = b_lds[qi];
            // nj0 tile
            {
                int r = r0;
                bool valid = (r >= qi) && (r <= qi + 31) && (s0 - (W_WIN - 1) + r >= 0);
                float g  = 1.0f / (1.0f + __expf(-(av0 * bgv)));
                float wt = valid ? c0[i] * scale * g : 0.0f;
                *(unsigned short*)(wb + swz(qi, r * 2)) = f2bf(wt);
            }
            // nj0+1 tile
            {
                int r = r1;
                bool valid = (r >= qi) && (r <= qi + 31) && (s0 - (W_WIN - 1) + r >= 0);
                float g  = 1.0f / (1.0f + __expf(-(av1 * bgv)));
                float wt = valid ? c1[i] * scale * g : 0.0f;
                *(unsigned short*)(wb + swz(qi, r * 2)) = f2bf(wt);
            }
        }
    }
    __syncthreads();

    // ---- PV: O[32 x 64] = W * V  (A = W row-major, B^T = vT) ----
    {
        bf16x8 aw0 = *(const bf16x8*)(wb + swz(mi * 16 + lr, lk * 16));
        bf16x8 aw1 = *(const bf16x8*)(wb + swz(mi * 16 + lr, lk * 16 + 64));
        f32x4 o0 = {0.f, 0.f, 0.f, 0.f};
        f32x4 o1 = {0.f, 0.f, 0.f, 0.f};
        bf16x8 v00 = *(const bf16x8*)(vtb + swz(nj0 * 16 + lr,      lk * 16));
        bf16x8 v01 = *(const bf16x8*)(vtb + swz(nj0 * 16 + lr,      lk * 16 + 64));
        bf16x8 v10 = *(const bf16x8*)(vtb + swz(nj0 * 16 + 16 + lr, lk * 16));
        bf16x8 v11 = *(const bf16x8*)(vtb + swz(nj0 * 16 + 16 + lr, lk * 16 + 64));
        o0 = __builtin_amdgcn_mfma_f32_16x16x32_bf16(aw0, v00, o0, 0, 0, 0);
        o0 = __builtin_amdgcn_mfma_f32_16x16x32_bf16(aw1, v01, o0, 0, 0, 0);
        o1 = __builtin_amdgcn_mfma_f32_16x16x32_bf16(aw0, v10, o1, 0, 0, 0);
        o1 = __builtin_amdgcn_mfma_f32_16x16x32_bf16(aw1, v11, o1, 0, 0, 0);

        #pragma unroll
        for (int i = 0; i < 4; ++i) {
            int qi = mi * 16 + lk * 4 + i;
            float* orow = out + ((size_t)(bb * S_LEN + s0 + qi)) * HD + (size_t)h * D_DIM;
            orow[nj0 * 16 + lr]      = o0[i];
            orow[nj0 * 16 + 16 + lr] = o1[i];
        }
    }
}

extern "C" void kernel_launch(void* const* d_in, const int* in_sizes, int n_in,
                              void* d_out, int out_size, void* d_ws, size_t ws_size,
                              hipStream_t stream) {
    const float* q  = (const float*)d_in[0];
    const float* k  = (const float*)d_in[1];
    const float* v  = (const float*)d_in[2];
    const float* a  = (const float*)d_in[3];
    const float* bg = (const float*)d_in[4];
    float* out = (float*)d_out;

    dim3 grid(2 /*B*/ * H_NUM * (S_LEN / TS));   // 1024 blocks (%8==0 for XCD swizzle)
    swa_gated_mfma<<<grid, 256, 0, stream>>>(q, k, v, a, bg, out);
}

// Round 4
// 11.624 us; speedup vs baseline: 1.5700x; 1.0085x over previous
//
#include <hip/hip_runtime.h>
#include <hip/hip_bf16.h>

#define S_LEN 2048
#define H_NUM 8
#define D_DIM 64
#define W_WIN 32
#define TS 64              // queries per block
#define NR  112            // staged k/v rows: [s0-31, s0+81), wave mi uses rows [16mi, 16mi+64)

typedef short bf16x8 __attribute__((ext_vector_type(8)));
typedef float f32x4  __attribute__((ext_vector_type(4)));

// 128-byte-row tiles (k_s, q_s, w_s): XOR bits 4-6 with row&7 -> 16-row reads are 2-way (free)
__device__ __forceinline__ int kswz(int row, int b) {
    return (row << 7) + (b ^ ((row & 7) << 4));
}
// vT tile: 256-byte rows, XOR bits 4-7 with d&15 -> 16-lane B-frag reads conflict-free
__device__ __forceinline__ int vswz(int d, int col) {
    return (d << 8) + ((col << 1) ^ ((d & 15) << 4));
}

__device__ __forceinline__ unsigned short f2bf(float x) {
    __hip_bfloat16 h = __float2bfloat16(x);
    return *reinterpret_cast<unsigned short*>(&h);
}

__global__ __launch_bounds__(256) void swa_gated_mfma2(
    const float* __restrict__ q, const float* __restrict__ k,
    const float* __restrict__ v, const float* __restrict__ a,
    const float* __restrict__ bgate, float* __restrict__ out)
{
    __shared__ __align__(16) unsigned short k_s[NR * 64];      // 14 KB, kswz
    __shared__ __align__(16) unsigned short vT_s[64 * 128];    // 16 KB, vswz (cols 0..111 used)
    __shared__ __align__(16) unsigned short q_s[TS * 64];      // 8 KB, kswz
    __shared__ __align__(16) unsigned short w_s[4 * 16 * 64];  // 2 KB/wave, kswz per-wave
    __shared__ float a_lds[NR];
    __shared__ float b_lds[TS];

    char* kb  = (char*)k_s;
    char* vtb = (char*)vT_s;
    char* qb  = (char*)q_s;
    char* wbch = (char*)w_s;

    const int tid = threadIdx.x;
    // bijective XCD swizzle (512 blocks % 8 == 0): XCD c gets 2 full heads -> 3 MB working set < 4 MB L2
    const int bid  = blockIdx.x;
    const int orig = ((bid & 7) << 6) | (bid >> 3);
    const int tile = orig & 31;          // 32 tiles of 64 queries
    const int h    = (orig >> 5) & 7;
    const int bb   = orig >> 8;
    const int s0   = tile * TS;
    const size_t HD = (size_t)H_NUM * D_DIM;   // 512

    // ---- stage k (row-major bf16) + v (transposed bf16), rows seq = s0-31+r, clamped ----
    #pragma unroll
    for (int it = 0; it < 7; ++it) {           // NR*16/256 = 7
        int idx = tid + it * 256;
        int r  = idx >> 4;
        int c4 = idx & 15;
        int seq = s0 - (W_WIN - 1) + r;
        int sc  = seq < 0 ? 0 : (seq > S_LEN - 1 ? S_LEN - 1 : seq);
        size_t base = ((size_t)(bb * S_LEN + sc)) * HD + (size_t)h * D_DIM + c4 * 4;
        float4 kv = *(const float4*)(k + base);
        float4 vv = *(const float4*)(v + base);
        union { unsigned short u[4]; uint2 p; } pk;
        pk.u[0] = f2bf(kv.x); pk.u[1] = f2bf(kv.y);
        pk.u[2] = f2bf(kv.z); pk.u[3] = f2bf(kv.w);
        *(uint2*)(kb + kswz(r, c4 * 8)) = pk.p;
        int d0 = c4 * 4;
        *(unsigned short*)(vtb + vswz(d0 + 0, r)) = f2bf(vv.x);
        *(unsigned short*)(vtb + vswz(d0 + 1, r)) = f2bf(vv.y);
        *(unsigned short*)(vtb + vswz(d0 + 2, r)) = f2bf(vv.z);
        *(unsigned short*)(vtb + vswz(d0 + 3, r)) = f2bf(vv.w);
    }
    // ---- stage q ----
    #pragma unroll
    for (int it = 0; it < 4; ++it) {           // TS*16/256 = 4
        int idx = tid + it * 256;
        int r  = idx >> 4;
        int c4 = idx & 15;
        size_t base = ((size_t)(bb * S_LEN + s0 + r)) * HD + (size_t)h * D_DIM + c4 * 4;
        float4 qv = *(const float4*)(q + base);
        union { unsigned short u[4]; uint2 p; } pq;
        pq.u[0] = f2bf(qv.x); pq.u[1] = f2bf(qv.y);
        pq.u[2] = f2bf(qv.z); pq.u[3] = f2bf(qv.w);
        *(uint2*)(qb + kswz(r, c4 * 8)) = pq.p;
    }
    if (tid < NR) {
        int seq = s0 - (W_WIN - 1) + tid;
        int sc  = seq < 0 ? 0 : (seq > S_LEN - 1 ? S_LEN - 1 : seq);
        a_lds[tid] = a[((size_t)(bb * S_LEN + sc)) * H_NUM + h];
    }
    if (tid < TS) {
        b_lds[tid] = bgate[((size_t)(bb * S_LEN + s0 + tid)) * H_NUM + h];
    }
    __syncthreads();   // the ONLY barrier: waves are independent from here on

    // ---- per-wave: 16 queries end-to-end. wave mi owns queries [16mi,16mi+16),
    //      staged-row window R in [16mi, 16mi+64) (band fits: needed max 16mi+46) ----
    const int mi = tid >> 6;
    const int l  = tid & 63;
    const int lr = l & 15;
    const int lk = l >> 4;
    char* wb = wbch + mi * 2048;

    // scores: S[16 x 64] = Q_mi * K_window^T
    bf16x8 aq0 = *(const bf16x8*)(qb + kswz(16 * mi + lr, lk * 16));
    bf16x8 aq1 = *(const bf16x8*)(qb + kswz(16 * mi + lr, lk * 16 + 64));
    f32x4 c[4];
    #pragma unroll
    for (int n = 0; n < 4; ++n) {
        int R = 16 * mi + 16 * n + lr;
        bf16x8 b0 = *(const bf16x8*)(kb + kswz(R, lk * 16));
        bf16x8 b1 = *(const bf16x8*)(kb + kswz(R, lk * 16 + 64));
        f32x4 z = {0.f, 0.f, 0.f, 0.f};
        z = __builtin_amdgcn_mfma_f32_16x16x32_bf16(aq0, b0, z, 0, 0, 0);
        c[n] = __builtin_amdgcn_mfma_f32_16x16x32_bf16(aq1, b1, z, 0, 0, 0);
    }

    // gate + band mask -> W (bf16, wave-local). select (not multiply): NaN-safe vs clamped rows
    const float scale = 0.125f;   // 1/sqrt(64)
    #pragma unroll
    for (int n = 0; n < 4; ++n) {
        int ccol = 16 * n + lr;            // 0..63 within wave window
        int R    = 16 * mi + ccol;
        float av = a_lds[R];
        int seqk = s0 - (W_WIN - 1) + R;
        #pragma unroll
        for (int i = 0; i < 4; ++i) {
            int qq = 4 * lk + i;           // query within wave
            bool valid = (ccol >= qq) && (ccol <= qq + 31) && (seqk >= 0);
            float g  = 1.0f / (1.0f + __expf(-(av * b_lds[16 * mi + qq])));
            float wt = valid ? c[n][i] * scale * g : 0.0f;
            *(unsigned short*)(wb + kswz(qq, ccol * 2)) = f2bf(wt);
        }
    }
    // wave-local LDS round-trip; compiler inserts lgkmcnt waits (no barrier needed)

    // PV: O[16 x 64] = W[16 x 64] * V[window 64 x 64]
    bf16x8 aw0 = *(const bf16x8*)(wb + kswz(lr, lk * 16));
    bf16x8 aw1 = *(const bf16x8*)(wb + kswz(lr, lk * 16 + 64));
    f32x4 o[4];
    #pragma unroll
    for (int n = 0; n < 4; ++n) {
        int d = 16 * n + lr;
        bf16x8 v0 = *(const bf16x8*)(vtb + vswz(d, 16 * mi + lk * 8));
        bf16x8 v1 = *(const bf16x8*)(vtb + vswz(d, 16 * mi + 32 + lk * 8));
        f32x4 z = {0.f, 0.f, 0.f, 0.f};
        z = __builtin_amdgcn_mfma_f32_16x16x32_bf16(aw0, v0, z, 0, 0, 0);
        o[n] = __builtin_amdgcn_mfma_f32_16x16x32_bf16(aw1, v1, o[n] = z, 0, 0, 0);
    }

    #pragma unroll
    for (int n = 0; n < 4; ++n) {
        #pragma unroll
        for (int i = 0; i < 4; ++i) {
            int qrow = s0 + 16 * mi + 4 * lk + i;
            out[((size_t)(bb * S_LEN + qrow)) * HD + (size_t)h * D_DIM + 16 * n + lr] = o[n][i];
        }
    }
}

extern "C" void kernel_launch(void* const* d_in, const int* in_sizes, int n_in,
                              void* d_out, int out_size, void* d_ws, size_t ws_size,
                              hipStream_t stream) {
    const float* q  = (const float*)d_in[0];
    const float* k  = (const float*)d_in[1];
    const float* v  = (const float*)d_in[2];
    const float* a  = (const float*)d_in[3];
    const float* bg = (const float*)d_in[4];
    float* out = (float*)d_out;

    dim3 grid(2 /*B*/ * H_NUM * (S_LEN / TS));   // 512 blocks, %8==0 for XCD swizzle
    swa_gated_mfma2<<<grid, 256, 0, stream>>>(q, k, v, a, bg, out);
}